// Round 7
// baseline (232.147 us; speedup 1.0000x reference)
//
#include <hip/hip_runtime.h>
#include <math.h>

#define TOKENS 16384
#define DMODEL 2048
#define NEXP   64
#define TOPK   8
#define KSPLIT 4
#define KCHUNK (DMODEL / KSPLIT)   // 512
#define NKS    (KCHUNK / 32)       // 16 k-steps per wave

typedef _Float16 half8 __attribute__((ext_vector_type(8)));
typedef float    f32x4 __attribute__((ext_vector_type(4)));

// fp32 -> fp16-pair (h + l) represents x to ~2^-24 relative (RTN twice).
// logits = sum over 3 MFMA passes (h*h' + l*h' + h*l'); dropped l*l' term is
// O(2^-24). fp32 MFMA accumulators flushed to fp64 every 4 k-steps (128 k):
// total error sigma ~2.5e-7 == numpy-pairwise-grade (same risk as the fp32
// kernel that passed R1-R6).

// Pre-kernel: swizzle W [64][2048] fp32 into fp16 h/l in MFMA B-fragment
// order. Fragment (ntile, kstep): lane holds W[n = nt*16 + (lane&15)]
// [k = ks*32 + (lane>>4)*8 + j], j=0..7 (m89/m120-verified 16x16x32 layout).
// Storage: wX[ ((nt*64 + ks)*64 + lane)*8 + j ]  -> 1 KB contiguous per frag,
// so gemm B-frag loads are single fully-coalesced dwordx4 per lane, L2-warm.
__global__ __launch_bounds__(64) void w_convert(
    const float* __restrict__ W, _Float16* __restrict__ wh,
    _Float16* __restrict__ wl)
{
    const int lane = threadIdx.x;
    const int nt   = blockIdx.x & 3;
    const int ks   = blockIdx.x >> 2;          // 0..63
    const int n    = nt * 16 + (lane & 15);
    const int k0   = ks * 32 + (lane >> 4) * 8;
    const size_t base = ((size_t)(nt * 64 + ks) * 64 + lane) * 8;
#pragma unroll
    for (int j = 0; j < 8; ++j) {
        const float w = W[(size_t)n * DMODEL + k0 + j];
        const _Float16 h = (_Float16)w;
        wh[base + j] = h;
        wl[base + j] = (_Float16)(w - (float)h);
    }
}

// Kernel 1: partial logits via MFMA. Wave = 16 tokens x 64 experts x KCHUNK.
// No LDS, no barriers: A-frags converted in-register from direct x loads
// (each lane reads its own 32B row segment, once); B-frags from L2-warm
// swizzled buffers. grid = (TOKENS/64, KSPLIT) -> 4096 waves = 16/CU.
__global__ __launch_bounds__(256) void router_gemm_mfma(
    const float* __restrict__ x, const _Float16* __restrict__ wh,
    const _Float16* __restrict__ wl, float* __restrict__ part)
{
    const int lane = threadIdx.x & 63;
    const int wid  = threadIdx.x >> 6;                 // 0..3
    const int kc   = blockIdx.y;
    const size_t tokBase = (size_t)blockIdx.x * 64 + wid * 16;
    const int m    = lane & 15;
    const int quad = lane >> 4;

    const float* xrow = x + (tokBase + m) * DMODEL + (size_t)kc * KCHUNK + quad * 8;

    f32x4 C[4];
    double accd[16];
#pragma unroll
    for (int nt = 0; nt < 4; ++nt) { C[nt] = (f32x4)0.0f; }
#pragma unroll
    for (int i = 0; i < 16; ++i) accd[i] = 0.0;

    for (int ks = 0; ks < NKS; ++ks) {
        // A: load 8 consecutive fp32, split into fp16 h/l fragments
        float xv[8];
        *(float4*)(&xv[0]) = *(const float4*)(xrow + ks * 32);
        *(float4*)(&xv[4]) = *(const float4*)(xrow + ks * 32 + 4);
        half8 ah, al;
#pragma unroll
        for (int j = 0; j < 8; ++j) {
            const _Float16 h = (_Float16)xv[j];
            ah[j] = h;
            al[j] = (_Float16)(xv[j] - (float)h);
        }
        // B: coalesced fragment loads (h and l) for 4 expert tiles
        const int gks = kc * NKS + ks;                 // global k-step 0..63
        half8 bh[4], bl[4];
#pragma unroll
        for (int nt = 0; nt < 4; ++nt) {
            const size_t fb = ((size_t)(nt * 64 + gks) * 64 + lane) * 8;
            bh[nt] = *(const half8*)(wh + fb);
            bl[nt] = *(const half8*)(wl + fb);
        }
        // 3 passes, nt-inner so each C chain has distance 4 (latency hiding)
#pragma unroll
        for (int nt = 0; nt < 4; ++nt)
            C[nt] = __builtin_amdgcn_mfma_f32_16x16x32_f16(ah, bh[nt], C[nt], 0, 0, 0);
#pragma unroll
        for (int nt = 0; nt < 4; ++nt)
            C[nt] = __builtin_amdgcn_mfma_f32_16x16x32_f16(al, bh[nt], C[nt], 0, 0, 0);
#pragma unroll
        for (int nt = 0; nt < 4; ++nt)
            C[nt] = __builtin_amdgcn_mfma_f32_16x16x32_f16(ah, bl[nt], C[nt], 0, 0, 0);

        if ((ks & 3) == 3) {   // flush fp32 C into fp64 every 128 k
#pragma unroll
            for (int nt = 0; nt < 4; ++nt) {
#pragma unroll
                for (int r = 0; r < 4; ++r) accd[nt * 4 + r] += (double)C[nt][r];
                C[nt] = (f32x4)0.0f;
            }
        }
    }

    // C/D layout (m89-verified): col = lane&15 (expert), row = quad*4 + reg
#pragma unroll
    for (int r = 0; r < 4; ++r) {
        const size_t tok = tokBase + quad * 4 + r;
#pragma unroll
        for (int nt = 0; nt < 4; ++nt) {
            part[((size_t)kc * TOKENS + tok) * NEXP + nt * 16 + m] =
                (float)accd[nt * 4 + r];
        }
    }
}

// Kernel 2: wave-per-token fused split-K reduce (fp64) + bias + top-8 + sigmoid.
// Lane e holds logit of expert e; comparisons on the fp32-CAST logit, ties
// broken toward lower index (lax.top_k stable order).
__global__ __launch_bounds__(256) void router_reduce_topk(
    const float* __restrict__ part, const float* __restrict__ bias,
    float* __restrict__ out_w, float* __restrict__ out_i, int ksplit)
{
    const int lane = threadIdx.x & 63;
    const int wid  = threadIdx.x >> 6;
    const size_t t = (size_t)blockIdx.x * 4 + wid;

    double vd = (double)bias[lane];
    for (int kc = 0; kc < ksplit; ++kc)
        vd += (double)part[((size_t)kc * TOKENS + t) * NEXP + lane];
    float v = (float)vd;

    const int myi = lane;
    float bv = 0.0f; int bi = 0;
#pragma unroll
    for (int r = 0; r < TOPK; ++r) {
        float mv = v; int mi = myi;
#pragma unroll
        for (int off = 32; off > 0; off >>= 1) {
            const float ov = __shfl_xor(mv, off, 64);
            const int   oi = __shfl_xor(mi, off, 64);
            if (ov > mv || (ov == mv && oi < mi)) { mv = ov; mi = oi; }
        }
        if (lane == r)  { bv = mv; bi = mi; }  // lane r keeps rank-r result
        if (myi == mi)  { v = -INFINITY; }     // remove winner (mi is uniform)
    }

    if (lane < TOPK) {
        out_w[t * TOPK + lane] = 1.0f / (1.0f + expf(-bv));
        out_i[t * TOPK + lane] = (float)bi;
    }
}

extern "C" void kernel_launch(void* const* d_in, const int* in_sizes, int n_in,
                              void* d_out, int out_size, void* d_ws, size_t ws_size,
                              hipStream_t stream) {
    const float* x    = (const float*)d_in[0];   // [4,4096,2048]
    const float* W    = (const float*)d_in[1];   // [64,2048]
    const float* bias = (const float*)d_in[2];   // [64]
    float* out_w = (float*)d_out;                          // [16384,8]
    float* out_i = (float*)d_out + (size_t)TOKENS * TOPK;  // [16384,8] as float

    // ws layout: part [KSPLIT][TOKENS][NEXP] fp32 (16 MB), then Wh, Wl fp16
    float*    part = (float*)d_ws;
    _Float16* wh   = (_Float16*)((char*)d_ws +
                       (size_t)KSPLIT * TOKENS * NEXP * sizeof(float));
    _Float16* wl   = wh + (size_t)NEXP * DMODEL;

    w_convert<<<256, 64, 0, stream>>>(W, wh, wl);
    dim3 grid(TOKENS / 64, KSPLIT);
    router_gemm_mfma<<<grid, 256, 0, stream>>>(x, wh, wl, part);
    router_reduce_topk<<<TOKENS / 4, 256, 0, stream>>>(part, bias, out_w, out_i, KSPLIT);
}